// Round 6
// baseline (228.531 us; speedup 1.0000x reference)
//
#include <hip/hip_runtime.h>

#define NB 4
#define CC 64
#define HW 4096
#define NT (NB*HW)
#define EPSV 1e-5f
#define LOG2E 1.4426950408889634f
#define THRV 8.0f   // defer-max threshold (exp2 domain): p <= 2^8, f16-safe

typedef _Float16 f16;
typedef _Float16 half4 __attribute__((ext_vector_type(4)));
typedef _Float16 half8 __attribute__((ext_vector_type(8)));
typedef float   float4v __attribute__((ext_vector_type(4)));

#define NELEM ((size_t)NB*HW*CC)   // 1,048,576 per tensor
#define NSLOT 128                  // conv2 partial-stat slots (NB * HW/128)

// ws: fp32 [512..512+NSLOT*256): per-(n,bx) partial BN stats.
// Byte 264192+: f16 q, k ([n][hw][c]) and gv ([n][c][hw]) — 3 x 2 MB.
#define PART_OFF 512
#define TEN_OFF  264192

// ---------------------------------------------------------------------------
// conv2: 3 fused 1x1 convs; 128 px/block (2 adjacent px per thread), 4-way
// channel split over blockIdx.z. grid (HW/128, NB, 4), 256 thr. (r12, kept)
// ---------------------------------------------------------------------------
__global__ __launch_bounds__(256)
void conv2_kernel(const float* __restrict__ x,
                  const float* __restrict__ h0, const float* __restrict__ h1,
                  const float* __restrict__ Wq, const float* __restrict__ bq,
                  const float* __restrict__ Wk, const float* __restrict__ bk,
                  const float* __restrict__ Wv, const float* __restrict__ bv,
                  float* __restrict__ ws,
                  f16* __restrict__ q, f16* __restrict__ k, f16* __restrict__ gv)
{
    __shared__ float Wl[3][16*CC];   // 12 KB
    __shared__ float xs[CC][128];    // 32 KB
    const int t    = threadIdx.x;
    const int n    = blockIdx.y;
    const int z    = blockIdx.z;
    const int px0  = blockIdx.x * 128;
    const int lane = t & 63;
    const int grp  = t >> 6;
    const int ocl  = grp * 4;
    const int oc0  = z*16 + ocl;

    ((float4*)Wl[0])[t] = ((const float4*)(Wq + (size_t)z*16*CC))[t];
    ((float4*)Wl[1])[t] = ((const float4*)(Wk + (size_t)z*16*CC))[t];
    ((float4*)Wl[2])[t] = ((const float4*)(Wv + (size_t)z*16*CC))[t];
    for (int i = t; i < CC*32; i += 256) {          // 2048 float4
        int ic = i >> 5, c4 = i & 31;
        ((float4*)&xs[ic][0])[c4] =
            ((const float4*)(x + ((size_t)n*CC + ic)*HW + px0))[c4];
    }
    __syncthreads();

    float aq[4][2], ak[4][2], av[4][2];
    #pragma unroll
    for (int j = 0; j < 4; ++j) {
        aq[j][0] = aq[j][1] = bq[oc0+j];
        ak[j][0] = ak[j][1] = bk[oc0+j];
        av[j][0] = av[j][1] = bv[oc0+j];
    }

    for (int ic = 0; ic < CC; ic += 4) {
        float2 xv0 = *(float2*)&xs[ic  ][lane*2];
        float2 xv1 = *(float2*)&xs[ic+1][lane*2];
        float2 xv2 = *(float2*)&xs[ic+2][lane*2];
        float2 xv3 = *(float2*)&xs[ic+3][lane*2];
        #pragma unroll
        for (int j = 0; j < 4; ++j) {
            const int row = (ocl+j)*CC + ic;
            float4 wq = *(const float4*)&Wl[0][row];
            float4 wk = *(const float4*)&Wl[1][row];
            float4 wv = *(const float4*)&Wl[2][row];
            aq[j][0] = fmaf(wq.x,xv0.x, fmaf(wq.y,xv1.x, fmaf(wq.z,xv2.x, fmaf(wq.w,xv3.x, aq[j][0]))));
            aq[j][1] = fmaf(wq.x,xv0.y, fmaf(wq.y,xv1.y, fmaf(wq.z,xv2.y, fmaf(wq.w,xv3.y, aq[j][1]))));
            ak[j][0] = fmaf(wk.x,xv0.x, fmaf(wk.y,xv1.x, fmaf(wk.z,xv2.x, fmaf(wk.w,xv3.x, ak[j][0]))));
            ak[j][1] = fmaf(wk.x,xv0.y, fmaf(wk.y,xv1.y, fmaf(wk.z,xv2.y, fmaf(wk.w,xv3.y, ak[j][1]))));
            av[j][0] = fmaf(wv.x,xv0.x, fmaf(wv.y,xv1.x, fmaf(wv.z,xv2.x, fmaf(wv.w,xv3.x, av[j][0]))));
            av[j][1] = fmaf(wv.x,xv0.y, fmaf(wv.y,xv1.y, fmaf(wv.z,xv2.y, fmaf(wv.w,xv3.y, av[j][1]))));
        }
    }

    const int px = px0 + lane*2;
    const size_t base = ((size_t)n*HW + px)*CC + oc0;
    half4 vq0, vq1, vk0, vk1;
    #pragma unroll
    for (int j = 0; j < 4; ++j) {
        vq0[j] = (f16)aq[j][0]; vq1[j] = (f16)aq[j][1];
        vk0[j] = (f16)ak[j][0]; vk1[j] = (f16)ak[j][1];
    }
    *(half4*)&q[base]      = vq0;  *(half4*)&q[base + CC] = vq1;
    *(half4*)&k[base]      = vk0;  *(half4*)&k[base + CC] = vk1;

    #pragma unroll
    for (int j = 0; j < 4; ++j) {
        size_t gi = ((size_t)n*CC + oc0 + j)*HW + px;
        f16 g0 = (f16)((h0[gi]   + h1[gi]  ) * av[j][0]);
        f16 g1 = (f16)((h0[gi+1] + h1[gi+1]) * av[j][1]);
        gv[gi]   = g0;
        gv[gi+1] = g1;
    }

    float* slot = ws + PART_OFF + (size_t)(n*(HW/128) + blockIdx.x)*256;
    #pragma unroll
    for (int j = 0; j < 4; ++j) {
        float v0 = aq[j][0] + aq[j][1];
        float v1 = aq[j][0]*aq[j][0] + aq[j][1]*aq[j][1];
        float v2 = ak[j][0] + ak[j][1];
        float v3 = ak[j][0]*ak[j][0] + ak[j][1]*ak[j][1];
        #pragma unroll
        for (int off = 32; off > 0; off >>= 1) {
            v0 += __shfl_down(v0, off);
            v1 += __shfl_down(v1, off);
            v2 += __shfl_down(v2, off);
            v3 += __shfl_down(v3, off);
        }
        if (lane == 0) {
            slot[      oc0 + j] = v0;
            slot[ 64 + oc0 + j] = v1;
            slot[128 + oc0 + j] = v2;
            slot[192 + oc0 + j] = v3;
        }
    }
}

// ---------------------------------------------------------------------------
// apply: folds BN stats redundantly per block, then y = relu(s*y+t) in place,
// 16 f16/thread. blockIdx.y: 0=q, 1=k (k pre-scaled by log2e). (r12, kept)
// ---------------------------------------------------------------------------
__global__ __launch_bounds__(256)
void apply_kernel(f16* __restrict__ q, f16* __restrict__ k,
                  const float* __restrict__ ws,
                  const float* __restrict__ gq, const float* __restrict__ betaq,
                  const float* __restrict__ gk, const float* __restrict__ betak)
{
    __shared__ float tot[128];
    __shared__ float sc[CC], sh[CC];
    const int t = threadIdx.x;
    const int tens = blockIdx.y;

    if (t < 128) {
        const float* base = ws + PART_OFF + tens*128 + t;
        float acc = 0.0f;
        #pragma unroll 8
        for (int s = 0; s < NSLOT; ++s) acc += base[(size_t)s*256];
        tot[t] = acc;
    }
    __syncthreads();
    if (t < 64) {
        float mean = tot[t] * (1.0f / NT);
        float var  = tot[64 + t] * (1.0f / NT) - mean*mean;
        if (tens == 0) {
            float s = gq[t] * rsqrtf(var + EPSV);
            sc[t] = s;  sh[t] = betaq[t] - mean*s;
        } else {
            float s = gk[t] * rsqrtf(var + EPSV);
            sc[t] = s * LOG2E;  sh[t] = (betak[t] - mean*s) * LOG2E;
        }
    }
    __syncthreads();

    f16* p = tens ? k : q;
    const size_t e0 = ((size_t)blockIdx.x * 256 + t) * 16;
    const int c0 = (int)(e0 & 63);

    half8 v0 = *(half8*)&p[e0], v1 = *(half8*)&p[e0 + 8];
    half8 o0, o1;
    #pragma unroll
    for (int j = 0; j < 8; ++j) {
        o0[j] = (f16)fmaxf(fmaf(sc[c0+j],   (float)v0[j], sh[c0+j]),   0.0f);
        o1[j] = (f16)fmaxf(fmaf(sc[c0+8+j], (float)v1[j], sh[c0+8+j]), 0.0f);
    }
    *(half8*)&p[e0]     = o0;
    *(half8*)&p[e0 + 8] = o1;
}

// ---------------------------------------------------------------------------
// MFMA flash attention — r19: K via shared LDS (64-key tiles), GV direct
// global->register fragments.
// r18 (K+GV both LDS-staged, 32-key tiles): 66 us, no spill, Occ 36%, but
// SQ_LDS_BANK_CONFLICT = 12.6M (~20 us/CU). Bank arithmetic: the GV
// ds_read_b64 pattern collides 4-way within 16-lane groups (bank-pair =
// f(m16&3) only); K b128 pattern (quad = kb^(m16&7)) is clean. Also 96 KB
// LDS moved per 32 keys.
// r19: (a) GV fragments load straight from global (r13-proven pattern; GV is
// L2-resident, ~512 MB L2 traffic ~ 15 us overlappable) — kills ALL GV LDS
// traffic + conflicts; (b) K tiles widen to 64 keys/barrier, both si-pair
// waves co-stage (qi half each) — staging instrs & barriers per key halved.
// LDS = K only: [4 si][2 buf][64x64] f16 = 64 KB; Obuf/MLbuf alias post-loop.
// Per-wave regs ~110 < 128 cap. Defer-max THR=8 + scalar accL kept (r17/r18
// validated). grid (HW/32, NB) = 512 blocks x 512 thr = 2 blocks/CU.
// SUCCESS CRITERIA: conflicts < 2M, WRITE_SIZE ~4 MB, attn < 55 us.
// Layout (validated r4-r18): mfma(X,Y) -> D[p=quad*4+reg <- X row][q=lane&15 <- Y row].
// ---------------------------------------------------------------------------
__global__ __launch_bounds__(512, 4)
void attn_kernel(const f16* __restrict__ q, const f16* __restrict__ k,
                 const f16* __restrict__ gv, float* __restrict__ out)
{
    __shared__ alignas(16) char SM[65536];
    f16 (* const Ks)[2][4096]    = reinterpret_cast<f16(*)[2][4096]>(SM);          // [si][buf][64*64]
    float (* const Obuf)[4][256] = reinterpret_cast<float(*)[4][256]>(SM);         // aliases Ks after loop
    float (* const MLbuf)[8][16] = reinterpret_cast<float(*)[8][16]>(SM + 32768);  // aliases Ks[2][0] (buf0, dead)

    const int t    = threadIdx.x;
    const int n    = blockIdx.y;
    const int w    = t >> 6;
    const int lane = t & 63;
    const int m16  = lane & 15;
    const int kb   = lane >> 4;
    const int qi   = w >> 2;                 // q-tile owner (0..1)
    const int si   = w & 3;                  // key-split (0..3)
    const int q0g  = blockIdx.x * 32 + qi * 16;

    // Q fragments: rows q0g+m16, channels kb*8 (+32)
    half8 qf0, qf1;
    {
        const size_t qb = ((size_t)n*HW + q0g + m16)*CC + kb*8;
        qf0 = *(const half8*)&q[qb];
        qf1 = *(const half8*)&q[qb + 32];
    }

    const f16* kn  = k  + (size_t)n*HW*CC;
    const f16* gvn = gv + (size_t)n*CC*HW;

    // K staging: wave covers rows qi*32 + rl + o*8 (o=0..3), col-chunk cl.
    const int rl    = lane >> 3, cl = lane & 7;
    const int rbase = qi*32 + rl;
    const size_t srcK = (size_t)rbase*CC + cl*8;
    const int    dstK = rbase*CC + ((cl ^ rl) * 8);   // (row&7)==rl for all o

    const int kt00 = si * 1024;

    // read-side swizzled element offsets (row&7 == m16&7 for all kg)
    const int e0k = ((kb     ^ (m16 & 7)) * 8);
    const int e1k = (((kb+4) ^ (m16 & 7)) * 8);

    half8 stg[4];
    half4 gvf[4][4];   // [kg][ct] — direct-global fragments for current tile

#define STAGE_LOAD(IT) do {                                                   \
    const f16* s_ = kn + (size_t)(kt00 + (IT)*64)*CC + srcK;                  \
    stg[0] = *(const half8*)(s_);                                             \
    stg[1] = *(const half8*)(s_ +  8*CC);                                     \
    stg[2] = *(const half8*)(s_ + 16*CC);                                     \
    stg[3] = *(const half8*)(s_ + 24*CC);                                     \
} while (0)

#define STAGE_WRITE(BUF) do {                                                 \
    f16* d_ = &Ks[si][BUF][dstK];                                             \
    *(half8*)(d_)        = stg[0];                                            \
    *(half8*)(d_ +  512) = stg[1];                                            \
    *(half8*)(d_ + 1024) = stg[2];                                            \
    *(half8*)(d_ + 1536) = stg[3];                                            \
} while (0)

    float4v accO[4];
    #pragma unroll
    for (int ct = 0; ct < 4; ++ct) accO[ct] = (float4v){0.f,0.f,0.f,0.f};
    float accL = 0.0f;
    float mreg = -INFINITY;

#define COMPUTE(CUR, IT) do {                                                 \
    const f16* Kb_ = &Ks[si][CUR][0];                                         \
    const int kt_ = kt00 + (IT)*64;                                           \
    float4v accS[4];                                                          \
    _Pragma("unroll") for (int kg_ = 0; kg_ < 4; ++kg_) {                     \
        const int r_ = (kg_*16 + m16)*CC;                                     \
        half8 kh0_ = *(const half8*)&Kb_[r_ + e0k];                           \
        half8 kh1_ = *(const half8*)&Kb_[r_ + e1k];                           \
        float4v s_ = {0.f,0.f,0.f,0.f};                                       \
        s_ = __builtin_amdgcn_mfma_f32_16x16x32_f16(kh0_, qf0, s_, 0,0,0);    \
        accS[kg_] = __builtin_amdgcn_mfma_f32_16x16x32_f16(kh1_, qf1, s_, 0,0,0); \
    }                                                                         \
    _Pragma("unroll") for (int kg_ = 0; kg_ < 4; ++kg_)                       \
    _Pragma("unroll") for (int ct_ = 0; ct_ < 4; ++ct_)                       \
        gvf[kg_][ct_] = *(const half4*)&gvn[(size_t)(ct_*16 + m16)*HW         \
                                            + kt_ + kg_*16 + kb*4];           \
    float v_ = fmaxf(fmaxf(fmaxf(accS[0][0],accS[0][1]), fmaxf(accS[0][2],accS[0][3])), \
                     fmaxf(fmaxf(accS[1][0],accS[1][1]), fmaxf(accS[1][2],accS[1][3]))); \
    float v2_ = fmaxf(fmaxf(fmaxf(accS[2][0],accS[2][1]), fmaxf(accS[2][2],accS[2][3])), \
                      fmaxf(fmaxf(accS[3][0],accS[3][1]), fmaxf(accS[3][2],accS[3][3]))); \
    v_ = fmaxf(v_, v2_);                                                      \
    v_ = fmaxf(v_, __shfl_xor(v_, 16));                                       \
    v_ = fmaxf(v_, __shfl_xor(v_, 32));                                       \
    if (__any(v_ > mreg + THRV)) {                                            \
        float mn_ = fmaxf(mreg, v_);                                          \
        float al_ = exp2f(mreg - mn_);                                        \
        mreg = mn_;  accL *= al_;                                             \
        _Pragma("unroll") for (int ct_ = 0; ct_ < 4; ++ct_) {                 \
            accO[ct_][0]*=al_; accO[ct_][1]*=al_;                             \
            accO[ct_][2]*=al_; accO[ct_][3]*=al_;                             \
        }                                                                     \
    }                                                                         \
    half4 pf_[4];                                                             \
    _Pragma("unroll") for (int kg_ = 0; kg_ < 4; ++kg_) {                     \
        float p0_=exp2f(accS[kg_][0]-mreg), p1_=exp2f(accS[kg_][1]-mreg);     \
        float p2_=exp2f(accS[kg_][2]-mreg), p3_=exp2f(accS[kg_][3]-mreg);     \
        accL += (p0_+p1_)+(p2_+p3_);                                          \
        pf_[kg_][0]=(f16)p0_; pf_[kg_][1]=(f16)p1_;                           \
        pf_[kg_][2]=(f16)p2_; pf_[kg_][3]=(f16)p3_;                           \
    }                                                                         \
    _Pragma("unroll") for (int ct_ = 0; ct_ < 4; ++ct_) {                     \
        float4v o_ = accO[ct_];                                               \
        o_ = __builtin_amdgcn_mfma_f32_16x16x16f16(gvf[0][ct_], pf_[0], o_, 0,0,0); \
        o_ = __builtin_amdgcn_mfma_f32_16x16x16f16(gvf[1][ct_], pf_[1], o_, 0,0,0); \
        o_ = __builtin_amdgcn_mfma_f32_16x16x16f16(gvf[2][ct_], pf_[2], o_, 0,0,0); \
        accO[ct_] = __builtin_amdgcn_mfma_f32_16x16x16f16(gvf[3][ct_], pf_[3], o_, 0,0,0); \
    }                                                                         \
} while (0)

    // prologue: tile 0 -> buf 0
    STAGE_LOAD(0);
    STAGE_WRITE(0);
    __syncthreads();

    for (int it = 0; it < 15; ++it) {
        const int cur = it & 1;
        STAGE_LOAD(it + 1);          // global latency hides under COMPUTE
        COMPUTE(cur, it);
        STAGE_WRITE(cur ^ 1);
        __syncthreads();
    }
    COMPUTE(1, 15);                  // tile 15 sits in buf 1

    // cross-quad l, publish (m, l) per q-row
    float lq = accL;
    lq += __shfl_xor(lq, 16);
    lq += __shfl_xor(lq, 32);
    if (kb == 0) {
        MLbuf[0][w][m16] = mreg;
        MLbuf[1][w][m16] = lq;
    }
    __syncthreads();

    // shared max frame for own q-tile; scale own partials
    const int wb = qi * 4;
    {
        float M_ = fmaxf(fmaxf(MLbuf[0][wb][m16],   MLbuf[0][wb+1][m16]),
                         fmaxf(MLbuf[0][wb+2][m16], MLbuf[0][wb+3][m16]));
        float f_ = exp2f(mreg - M_);
        #pragma unroll
        for (int ct = 0; ct < 4; ++ct) {
            accO[ct][0]*=f_; accO[ct][1]*=f_; accO[ct][2]*=f_; accO[ct][3]*=f_;
        }
    }
    #pragma unroll
    for (int ct = 0; ct < 4; ++ct)
        ((float4*)&Obuf[w][ct][0])[lane] =
            (float4){accO[ct][0], accO[ct][1], accO[ct][2], accO[ct][3]};
    __syncthreads();

    // sum over si and write: wave w handles (q-tile w>>2, ct w&3)
    {
        const int qi2 = w >> 2, ct2 = w & 3, wb2 = qi2 * 4;
        float4 s  = ((float4*)&Obuf[wb2  ][ct2][0])[lane];
        float4 a1 = ((float4*)&Obuf[wb2+1][ct2][0])[lane];
        float4 a2 = ((float4*)&Obuf[wb2+2][ct2][0])[lane];
        float4 a3 = ((float4*)&Obuf[wb2+3][ct2][0])[lane];
        s.x += a1.x + a2.x + a3.x;
        s.y += a1.y + a2.y + a3.y;
        s.z += a1.z + a2.z + a3.z;
        s.w += a1.w + a2.w + a3.w;
        float m0 = MLbuf[0][wb2  ][m16], m1 = MLbuf[0][wb2+1][m16];
        float m2 = MLbuf[0][wb2+2][m16], m3 = MLbuf[0][wb2+3][m16];
        float M_ = fmaxf(fmaxf(m0, m1), fmaxf(m2, m3));
        float L_ = MLbuf[1][wb2  ][m16] * exp2f(m0 - M_)
                 + MLbuf[1][wb2+1][m16] * exp2f(m1 - M_)
                 + MLbuf[1][wb2+2][m16] * exp2f(m2 - M_)
                 + MLbuf[1][wb2+3][m16] * exp2f(m3 - M_);
        const float iv = 1.0f / L_;
        const int chb = ct2*16 + kb*4;
        const int row = blockIdx.x*32 + qi2*16 + m16;
        out[((size_t)n*CC + chb + 0)*HW + row] = s.x * iv;
        out[((size_t)n*CC + chb + 1)*HW + row] = s.y * iv;
        out[((size_t)n*CC + chb + 2)*HW + row] = s.z * iv;
        out[((size_t)n*CC + chb + 3)*HW + row] = s.w * iv;
    }
#undef COMPUTE
#undef STAGE_WRITE
#undef STAGE_LOAD
}

// ---------------------------------------------------------------------------
extern "C" void kernel_launch(void* const* d_in, const int* in_sizes, int n_in,
                              void* d_out, int out_size, void* d_ws, size_t ws_size,
                              hipStream_t stream)
{
    const float* low   = (const float*)d_in[0];
    const float* h0    = (const float*)d_in[1];
    const float* h1    = (const float*)d_in[2];
    const float* Wq    = (const float*)d_in[3];
    const float* bq    = (const float*)d_in[4];
    const float* gq    = (const float*)d_in[5];
    const float* betaq = (const float*)d_in[6];
    const float* Wk    = (const float*)d_in[7];
    const float* bk    = (const float*)d_in[8];
    const float* gk    = (const float*)d_in[9];
    const float* betak = (const float*)d_in[10];
    const float* Wv    = (const float*)d_in[11];
    const float* bv    = (const float*)d_in[12];

    float* wsf = (float*)d_ws;
    float* out = (float*)d_out;

    f16* q  = (f16*)((char*)d_ws + TEN_OFF);
    f16* k  = q + NELEM;
    f16* gv = k + NELEM;

    conv2_kernel<<<dim3(HW/128, NB, 4), 256, 0, stream>>>(
        low, h0, h1, Wq, bq, Wk, bk, Wv, bv, wsf, q, k, gv);

    apply_kernel<<<dim3((int)(NELEM/(256*16)), 2), 256, 0, stream>>>(
        q, k, wsf, gq, betaq, gk, betak);

    attn_kernel<<<dim3(HW/32, NB), 512, 0, stream>>>(q, k, gv, out);
}

// Round 7
// 227.258 us; speedup vs baseline: 1.0056x; 1.0056x over previous
//
#include <hip/hip_runtime.h>

#define NB 4
#define CC 64
#define HW 4096
#define NT (NB*HW)
#define EPSV 1e-5f
#define LOG2E 1.4426950408889634f
#define THRV 8.0f   // defer-max threshold (exp2 domain): p <= 2^8, f16-safe

typedef _Float16 f16;
typedef _Float16 half4 __attribute__((ext_vector_type(4)));
typedef _Float16 half8 __attribute__((ext_vector_type(8)));
typedef float   float4v __attribute__((ext_vector_type(4)));

#define NELEM ((size_t)NB*HW*CC)   // 1,048,576 per tensor
#define NSLOT 128                  // conv2 partial-stat slots (NB * HW/128)

// ws: fp32 [512..512+NSLOT*256): per-(n,bx) partial BN stats.
// Byte 264192+: f16 q, k ([n][hw][c]) and gv ([n][c][hw]) — 3 x 2 MB.
#define PART_OFF 512
#define TEN_OFF  264192

// ---------------------------------------------------------------------------
// conv2: 3 fused 1x1 convs; 128 px/block (2 adjacent px per thread), 4-way
// channel split over blockIdx.z. grid (HW/128, NB, 4), 256 thr. (r12, kept)
// ---------------------------------------------------------------------------
__global__ __launch_bounds__(256)
void conv2_kernel(const float* __restrict__ x,
                  const float* __restrict__ h0, const float* __restrict__ h1,
                  const float* __restrict__ Wq, const float* __restrict__ bq,
                  const float* __restrict__ Wk, const float* __restrict__ bk,
                  const float* __restrict__ Wv, const float* __restrict__ bv,
                  float* __restrict__ ws,
                  f16* __restrict__ q, f16* __restrict__ k, f16* __restrict__ gv)
{
    __shared__ float Wl[3][16*CC];   // 12 KB
    __shared__ float xs[CC][128];    // 32 KB
    const int t    = threadIdx.x;
    const int n    = blockIdx.y;
    const int z    = blockIdx.z;
    const int px0  = blockIdx.x * 128;
    const int lane = t & 63;
    const int grp  = t >> 6;
    const int ocl  = grp * 4;
    const int oc0  = z*16 + ocl;

    ((float4*)Wl[0])[t] = ((const float4*)(Wq + (size_t)z*16*CC))[t];
    ((float4*)Wl[1])[t] = ((const float4*)(Wk + (size_t)z*16*CC))[t];
    ((float4*)Wl[2])[t] = ((const float4*)(Wv + (size_t)z*16*CC))[t];
    for (int i = t; i < CC*32; i += 256) {          // 2048 float4
        int ic = i >> 5, c4 = i & 31;
        ((float4*)&xs[ic][0])[c4] =
            ((const float4*)(x + ((size_t)n*CC + ic)*HW + px0))[c4];
    }
    __syncthreads();

    float aq[4][2], ak[4][2], av[4][2];
    #pragma unroll
    for (int j = 0; j < 4; ++j) {
        aq[j][0] = aq[j][1] = bq[oc0+j];
        ak[j][0] = ak[j][1] = bk[oc0+j];
        av[j][0] = av[j][1] = bv[oc0+j];
    }

    for (int ic = 0; ic < CC; ic += 4) {
        float2 xv0 = *(float2*)&xs[ic  ][lane*2];
        float2 xv1 = *(float2*)&xs[ic+1][lane*2];
        float2 xv2 = *(float2*)&xs[ic+2][lane*2];
        float2 xv3 = *(float2*)&xs[ic+3][lane*2];
        #pragma unroll
        for (int j = 0; j < 4; ++j) {
            const int row = (ocl+j)*CC + ic;
            float4 wq = *(const float4*)&Wl[0][row];
            float4 wk = *(const float4*)&Wl[1][row];
            float4 wv = *(const float4*)&Wl[2][row];
            aq[j][0] = fmaf(wq.x,xv0.x, fmaf(wq.y,xv1.x, fmaf(wq.z,xv2.x, fmaf(wq.w,xv3.x, aq[j][0]))));
            aq[j][1] = fmaf(wq.x,xv0.y, fmaf(wq.y,xv1.y, fmaf(wq.z,xv2.y, fmaf(wq.w,xv3.y, aq[j][1]))));
            ak[j][0] = fmaf(wk.x,xv0.x, fmaf(wk.y,xv1.x, fmaf(wk.z,xv2.x, fmaf(wk.w,xv3.x, ak[j][0]))));
            ak[j][1] = fmaf(wk.x,xv0.y, fmaf(wk.y,xv1.y, fmaf(wk.z,xv2.y, fmaf(wk.w,xv3.y, ak[j][1]))));
            av[j][0] = fmaf(wv.x,xv0.x, fmaf(wv.y,xv1.x, fmaf(wv.z,xv2.x, fmaf(wv.w,xv3.x, av[j][0]))));
            av[j][1] = fmaf(wv.x,xv0.y, fmaf(wv.y,xv1.y, fmaf(wv.z,xv2.y, fmaf(wv.w,xv3.y, av[j][1]))));
        }
    }

    const int px = px0 + lane*2;
    const size_t base = ((size_t)n*HW + px)*CC + oc0;
    half4 vq0, vq1, vk0, vk1;
    #pragma unroll
    for (int j = 0; j < 4; ++j) {
        vq0[j] = (f16)aq[j][0]; vq1[j] = (f16)aq[j][1];
        vk0[j] = (f16)ak[j][0]; vk1[j] = (f16)ak[j][1];
    }
    *(half4*)&q[base]      = vq0;  *(half4*)&q[base + CC] = vq1;
    *(half4*)&k[base]      = vk0;  *(half4*)&k[base + CC] = vk1;

    #pragma unroll
    for (int j = 0; j < 4; ++j) {
        size_t gi = ((size_t)n*CC + oc0 + j)*HW + px;
        f16 g0 = (f16)((h0[gi]   + h1[gi]  ) * av[j][0]);
        f16 g1 = (f16)((h0[gi+1] + h1[gi+1]) * av[j][1]);
        gv[gi]   = g0;
        gv[gi+1] = g1;
    }

    float* slot = ws + PART_OFF + (size_t)(n*(HW/128) + blockIdx.x)*256;
    #pragma unroll
    for (int j = 0; j < 4; ++j) {
        float v0 = aq[j][0] + aq[j][1];
        float v1 = aq[j][0]*aq[j][0] + aq[j][1]*aq[j][1];
        float v2 = ak[j][0] + ak[j][1];
        float v3 = ak[j][0]*ak[j][0] + ak[j][1]*ak[j][1];
        #pragma unroll
        for (int off = 32; off > 0; off >>= 1) {
            v0 += __shfl_down(v0, off);
            v1 += __shfl_down(v1, off);
            v2 += __shfl_down(v2, off);
            v3 += __shfl_down(v3, off);
        }
        if (lane == 0) {
            slot[      oc0 + j] = v0;
            slot[ 64 + oc0 + j] = v1;
            slot[128 + oc0 + j] = v2;
            slot[192 + oc0 + j] = v3;
        }
    }
}

// ---------------------------------------------------------------------------
// apply: folds BN stats redundantly per block, then y = relu(s*y+t) in place,
// 16 f16/thread. blockIdx.y: 0=q, 1=k (k pre-scaled by log2e). (r12, kept)
// ---------------------------------------------------------------------------
__global__ __launch_bounds__(256)
void apply_kernel(f16* __restrict__ q, f16* __restrict__ k,
                  const float* __restrict__ ws,
                  const float* __restrict__ gq, const float* __restrict__ betaq,
                  const float* __restrict__ gk, const float* __restrict__ betak)
{
    __shared__ float tot[128];
    __shared__ float sc[CC], sh[CC];
    const int t = threadIdx.x;
    const int tens = blockIdx.y;

    if (t < 128) {
        const float* base = ws + PART_OFF + tens*128 + t;
        float acc = 0.0f;
        #pragma unroll 8
        for (int s = 0; s < NSLOT; ++s) acc += base[(size_t)s*256];
        tot[t] = acc;
    }
    __syncthreads();
    if (t < 64) {
        float mean = tot[t] * (1.0f / NT);
        float var  = tot[64 + t] * (1.0f / NT) - mean*mean;
        if (tens == 0) {
            float s = gq[t] * rsqrtf(var + EPSV);
            sc[t] = s;  sh[t] = betaq[t] - mean*s;
        } else {
            float s = gk[t] * rsqrtf(var + EPSV);
            sc[t] = s * LOG2E;  sh[t] = (betak[t] - mean*s) * LOG2E;
        }
    }
    __syncthreads();

    f16* p = tens ? k : q;
    const size_t e0 = ((size_t)blockIdx.x * 256 + t) * 16;
    const int c0 = (int)(e0 & 63);

    half8 v0 = *(half8*)&p[e0], v1 = *(half8*)&p[e0 + 8];
    half8 o0, o1;
    #pragma unroll
    for (int j = 0; j < 8; ++j) {
        o0[j] = (f16)fmaxf(fmaf(sc[c0+j],   (float)v0[j], sh[c0+j]),   0.0f);
        o1[j] = (f16)fmaxf(fmaf(sc[c0+8+j], (float)v1[j], sh[c0+8+j]), 0.0f);
    }
    *(half8*)&p[e0]     = o0;
    *(half8*)&p[e0 + 8] = o1;
}

// ---------------------------------------------------------------------------
// MFMA flash attention — r20: r19 with the gvf loads hoisted ABOVE the K
// staging loads (vmcnt ordering fix).
// r19 post-mortem: conflicts 12.6M -> 0 (GV-conflict theory confirmed) but
// 135 us, MfmaUtil 7%. Cause: vmcnt is an ORDERED counter. r19 issued
// STAGE_LOAD(it+1) (K, global) BEFORE the gvf loads (inside COMPUTE), so
// PV's wait on gvf == vmcnt(0) == wait for next-tile K too — the K prefetch
// was serialized into compute; every tile paid full K+GV latency.
// r20: loop body order = GVLOAD(it) -> STAGE_LOAD(it+1) -> COMPUTE -> 
// STAGE_WRITE -> barrier. PV's gvf wait is now vmcnt(4): the 4 K loads stay
// in flight across COMPUTE; gvf has QK+softmax (~250cy) slack + 4 waves/SIMD
// TLP. No new registers vs r19 (gvf lives longer: VGPR ~90-105 expected).
// SUCCESS CRITERIA: WRITE_SIZE ~4 MB, conflicts ~0, MfmaUtil > 15%,
// attn < 55 us (beats r13's 66).
// Layout (validated r4-r18): mfma(X,Y) -> D[p=quad*4+reg <- X row][q=lane&15 <- Y row].
// ---------------------------------------------------------------------------
__global__ __launch_bounds__(512, 4)
void attn_kernel(const f16* __restrict__ q, const f16* __restrict__ k,
                 const f16* __restrict__ gv, float* __restrict__ out)
{
    __shared__ alignas(16) char SM[65536];
    f16 (* const Ks)[2][4096]    = reinterpret_cast<f16(*)[2][4096]>(SM);          // [si][buf][64*64]
    float (* const Obuf)[4][256] = reinterpret_cast<float(*)[4][256]>(SM);         // aliases Ks after loop
    float (* const MLbuf)[8][16] = reinterpret_cast<float(*)[8][16]>(SM + 32768);  // aliases Ks[2][0] (buf0, dead)

    const int t    = threadIdx.x;
    const int n    = blockIdx.y;
    const int w    = t >> 6;
    const int lane = t & 63;
    const int m16  = lane & 15;
    const int kb   = lane >> 4;
    const int qi   = w >> 2;                 // q-tile owner (0..1)
    const int si   = w & 3;                  // key-split (0..3)
    const int q0g  = blockIdx.x * 32 + qi * 16;

    // Q fragments: rows q0g+m16, channels kb*8 (+32)
    half8 qf0, qf1;
    {
        const size_t qb = ((size_t)n*HW + q0g + m16)*CC + kb*8;
        qf0 = *(const half8*)&q[qb];
        qf1 = *(const half8*)&q[qb + 32];
    }

    const f16* kn  = k  + (size_t)n*HW*CC;
    const f16* gvn = gv + (size_t)n*CC*HW;

    // K staging: wave covers rows qi*32 + rl + o*8 (o=0..3), col-chunk cl.
    const int rl    = lane >> 3, cl = lane & 7;
    const int rbase = qi*32 + rl;
    const size_t srcK = (size_t)rbase*CC + cl*8;
    const int    dstK = rbase*CC + ((cl ^ rl) * 8);   // (row&7)==rl for all o

    const int kt00 = si * 1024;

    // read-side swizzled element offsets (row&7 == m16&7 for all kg)
    const int e0k = ((kb     ^ (m16 & 7)) * 8);
    const int e1k = (((kb+4) ^ (m16 & 7)) * 8);

    half8 stg[4];
    half4 gvf[4][4];   // [kg][ct] — direct-global fragments for current tile

#define GVLOAD(IT) do {                                                       \
    const int kt_ = kt00 + (IT)*64;                                           \
    _Pragma("unroll") for (int kg_ = 0; kg_ < 4; ++kg_)                       \
    _Pragma("unroll") for (int ct_ = 0; ct_ < 4; ++ct_)                       \
        gvf[kg_][ct_] = *(const half4*)&gvn[(size_t)(ct_*16 + m16)*HW         \
                                            + kt_ + kg_*16 + kb*4];           \
} while (0)

#define STAGE_LOAD(IT) do {                                                   \
    const f16* s_ = kn + (size_t)(kt00 + (IT)*64)*CC + srcK;                  \
    stg[0] = *(const half8*)(s_);                                             \
    stg[1] = *(const half8*)(s_ +  8*CC);                                     \
    stg[2] = *(const half8*)(s_ + 16*CC);                                     \
    stg[3] = *(const half8*)(s_ + 24*CC);                                     \
} while (0)

#define STAGE_WRITE(BUF) do {                                                 \
    f16* d_ = &Ks[si][BUF][dstK];                                             \
    *(half8*)(d_)        = stg[0];                                            \
    *(half8*)(d_ +  512) = stg[1];                                            \
    *(half8*)(d_ + 1024) = stg[2];                                            \
    *(half8*)(d_ + 1536) = stg[3];                                            \
} while (0)

    float4v accO[4];
    #pragma unroll
    for (int ct = 0; ct < 4; ++ct) accO[ct] = (float4v){0.f,0.f,0.f,0.f};
    float accL = 0.0f;
    float mreg = -INFINITY;

#define COMPUTE(CUR) do {                                                     \
    const f16* Kb_ = &Ks[si][CUR][0];                                         \
    float4v accS[4];                                                          \
    _Pragma("unroll") for (int kg_ = 0; kg_ < 4; ++kg_) {                     \
        const int r_ = (kg_*16 + m16)*CC;                                     \
        half8 kh0_ = *(const half8*)&Kb_[r_ + e0k];                           \
        half8 kh1_ = *(const half8*)&Kb_[r_ + e1k];                           \
        float4v s_ = {0.f,0.f,0.f,0.f};                                       \
        s_ = __builtin_amdgcn_mfma_f32_16x16x32_f16(kh0_, qf0, s_, 0,0,0);    \
        accS[kg_] = __builtin_amdgcn_mfma_f32_16x16x32_f16(kh1_, qf1, s_, 0,0,0); \
    }                                                                         \
    float v_ = fmaxf(fmaxf(fmaxf(accS[0][0],accS[0][1]), fmaxf(accS[0][2],accS[0][3])), \
                     fmaxf(fmaxf(accS[1][0],accS[1][1]), fmaxf(accS[1][2],accS[1][3]))); \
    float v2_ = fmaxf(fmaxf(fmaxf(accS[2][0],accS[2][1]), fmaxf(accS[2][2],accS[2][3])), \
                      fmaxf(fmaxf(accS[3][0],accS[3][1]), fmaxf(accS[3][2],accS[3][3]))); \
    v_ = fmaxf(v_, v2_);                                                      \
    v_ = fmaxf(v_, __shfl_xor(v_, 16));                                       \
    v_ = fmaxf(v_, __shfl_xor(v_, 32));                                       \
    if (__any(v_ > mreg + THRV)) {                                            \
        float mn_ = fmaxf(mreg, v_);                                          \
        float al_ = exp2f(mreg - mn_);                                        \
        mreg = mn_;  accL *= al_;                                             \
        _Pragma("unroll") for (int ct_ = 0; ct_ < 4; ++ct_) {                 \
            accO[ct_][0]*=al_; accO[ct_][1]*=al_;                             \
            accO[ct_][2]*=al_; accO[ct_][3]*=al_;                             \
        }                                                                     \
    }                                                                         \
    half4 pf_[4];                                                             \
    _Pragma("unroll") for (int kg_ = 0; kg_ < 4; ++kg_) {                     \
        float p0_=exp2f(accS[kg_][0]-mreg), p1_=exp2f(accS[kg_][1]-mreg);     \
        float p2_=exp2f(accS[kg_][2]-mreg), p3_=exp2f(accS[kg_][3]-mreg);     \
        accL += (p0_+p1_)+(p2_+p3_);                                          \
        pf_[kg_][0]=(f16)p0_; pf_[kg_][1]=(f16)p1_;                           \
        pf_[kg_][2]=(f16)p2_; pf_[kg_][3]=(f16)p3_;                           \
    }                                                                         \
    _Pragma("unroll") for (int ct_ = 0; ct_ < 4; ++ct_) {                     \
        float4v o_ = accO[ct_];                                               \
        o_ = __builtin_amdgcn_mfma_f32_16x16x16f16(gvf[0][ct_], pf_[0], o_, 0,0,0); \
        o_ = __builtin_amdgcn_mfma_f32_16x16x16f16(gvf[1][ct_], pf_[1], o_, 0,0,0); \
        o_ = __builtin_amdgcn_mfma_f32_16x16x16f16(gvf[2][ct_], pf_[2], o_, 0,0,0); \
        accO[ct_] = __builtin_amdgcn_mfma_f32_16x16x16f16(gvf[3][ct_], pf_[3], o_, 0,0,0); \
    }                                                                         \
} while (0)

    // prologue: K tile 0 -> buf 0
    STAGE_LOAD(0);
    STAGE_WRITE(0);
    __syncthreads();

    for (int it = 0; it < 15; ++it) {
        const int cur = it & 1;
        GVLOAD(it);                  // oldest in vmcnt queue — PV waits vmcnt(4)
        STAGE_LOAD(it + 1);          // stays in flight across COMPUTE
        COMPUTE(cur);
        STAGE_WRITE(cur ^ 1);        // vmcnt(0) for stg, ~350cy after issue
        __syncthreads();
    }
    GVLOAD(15);
    COMPUTE(1);                      // tile 15 sits in buf 1

    // cross-quad l, publish (m, l) per q-row
    float lq = accL;
    lq += __shfl_xor(lq, 16);
    lq += __shfl_xor(lq, 32);
    if (kb == 0) {
        MLbuf[0][w][m16] = mreg;
        MLbuf[1][w][m16] = lq;
    }
    __syncthreads();

    // shared max frame for own q-tile; scale own partials
    const int wb = qi * 4;
    {
        float M_ = fmaxf(fmaxf(MLbuf[0][wb][m16],   MLbuf[0][wb+1][m16]),
                         fmaxf(MLbuf[0][wb+2][m16], MLbuf[0][wb+3][m16]));
        float f_ = exp2f(mreg - M_);
        #pragma unroll
        for (int ct = 0; ct < 4; ++ct) {
            accO[ct][0]*=f_; accO[ct][1]*=f_; accO[ct][2]*=f_; accO[ct][3]*=f_;
        }
    }
    #pragma unroll
    for (int ct = 0; ct < 4; ++ct)
        ((float4*)&Obuf[w][ct][0])[lane] =
            (float4){accO[ct][0], accO[ct][1], accO[ct][2], accO[ct][3]};
    __syncthreads();

    // sum over si and write: wave w handles (q-tile w>>2, ct w&3)
    {
        const int qi2 = w >> 2, ct2 = w & 3, wb2 = qi2 * 4;
        float4 s  = ((float4*)&Obuf[wb2  ][ct2][0])[lane];
        float4 a1 = ((float4*)&Obuf[wb2+1][ct2][0])[lane];
        float4 a2 = ((float4*)&Obuf[wb2+2][ct2][0])[lane];
        float4 a3 = ((float4*)&Obuf[wb2+3][ct2][0])[lane];
        s.x += a1.x + a2.x + a3.x;
        s.y += a1.y + a2.y + a3.y;
        s.z += a1.z + a2.z + a3.z;
        s.w += a1.w + a2.w + a3.w;
        float m0 = MLbuf[0][wb2  ][m16], m1 = MLbuf[0][wb2+1][m16];
        float m2 = MLbuf[0][wb2+2][m16], m3 = MLbuf[0][wb2+3][m16];
        float M_ = fmaxf(fmaxf(m0, m1), fmaxf(m2, m3));
        float L_ = MLbuf[1][wb2  ][m16] * exp2f(m0 - M_)
                 + MLbuf[1][wb2+1][m16] * exp2f(m1 - M_)
                 + MLbuf[1][wb2+2][m16] * exp2f(m2 - M_)
                 + MLbuf[1][wb2+3][m16] * exp2f(m3 - M_);
        const float iv = 1.0f / L_;
        const int chb = ct2*16 + kb*4;
        const int row = blockIdx.x*32 + qi2*16 + m16;
        out[((size_t)n*CC + chb + 0)*HW + row] = s.x * iv;
        out[((size_t)n*CC + chb + 1)*HW + row] = s.y * iv;
        out[((size_t)n*CC + chb + 2)*HW + row] = s.z * iv;
        out[((size_t)n*CC + chb + 3)*HW + row] = s.w * iv;
    }
#undef COMPUTE
#undef STAGE_WRITE
#undef STAGE_LOAD
#undef GVLOAD
}

// ---------------------------------------------------------------------------
extern "C" void kernel_launch(void* const* d_in, const int* in_sizes, int n_in,
                              void* d_out, int out_size, void* d_ws, size_t ws_size,
                              hipStream_t stream)
{
    const float* low   = (const float*)d_in[0];
    const float* h0    = (const float*)d_in[1];
    const float* h1    = (const float*)d_in[2];
    const float* Wq    = (const float*)d_in[3];
    const float* bq    = (const float*)d_in[4];
    const float* gq    = (const float*)d_in[5];
    const float* betaq = (const float*)d_in[6];
    const float* Wk    = (const float*)d_in[7];
    const float* bk    = (const float*)d_in[8];
    const float* gk    = (const float*)d_in[9];
    const float* betak = (const float*)d_in[10];
    const float* Wv    = (const float*)d_in[11];
    const float* bv    = (const float*)d_in[12];

    float* wsf = (float*)d_ws;
    float* out = (float*)d_out;

    f16* q  = (f16*)((char*)d_ws + TEN_OFF);
    f16* k  = q + NELEM;
    f16* gv = k + NELEM;

    conv2_kernel<<<dim3(HW/128, NB, 4), 256, 0, stream>>>(
        low, h0, h1, Wq, bq, Wk, bk, Wv, bv, wsf, q, k, gv);

    apply_kernel<<<dim3((int)(NELEM/(256*16)), 2), 256, 0, stream>>>(
        q, k, wsf, gq, betaq, gk, betak);

    attn_kernel<<<dim3(HW/32, NB), 512, 0, stream>>>(q, k, gv, out);
}